// Round 12
// baseline (85.102 us; speedup 1.0000x reference)
//
#include <hip/hip_runtime.h>

#define N_NODES  100000
#define N_EDGES  1600000
#define D        128
#define NG       64
#define NC       10
#define NBMAX    512      // gemm grid: 2 blocks/CU (1024 thr each)
#define TILE     64       // nodes per LDS tile
#define EPT      8        // edges per thread in bucket_kernel
#define ABLK     196      // ceil(N_EDGES / (1024*EPT))
#define NBUCK    391      // ceil(N_NODES / 256) src buckets
#define BCAP     8192     // u16 slots per bucket (empirically sufficient r6-r11)
#define XBLK     196      // node-role blocks (512 nodes each)
#define CIW16    72       // ci16 row stride (u16): 144B rows -> aligned b128
#define XSW      130      // xsp row stride (u32)

typedef unsigned int uint;
typedef unsigned short ushort;
typedef unsigned long long ull;
typedef short bhalf8 __attribute__((ext_vector_type(8)));
typedef float f32x4  __attribute__((ext_vector_type(4)));

#define MFMA_BF16 __builtin_amdgcn_mfma_f32_16x16x32_bf16

// ws layout (u32 units)
#define OFF_COUNTS 391
#define OFF_AGGX   512                    // 8192 floats (self-sum accumulator)
#define ZERO_U32   8704                   // [tail|counts|pad|aggX|pad) zeroed
#define BDATA_U32  (NBUCK * (BCAP / 2))   // 1,601,536

static_assert(ABLK * 1024 * EPT >= N_EDGES, "edge coverage");
static_assert(NBUCK * 256 >= N_NODES, "bucket coverage");
static_assert(XBLK * 512 >= N_NODES, "node coverage");

// ---------------------------------------------------------------------------
// Kernel 0: zero tail + counts + aggX.
// ---------------------------------------------------------------------------
__global__ __launch_bounds__(256) void fill_kernel(uint* __restrict__ p)
{
    const int i = blockIdx.x * 256 + threadIdx.x;
    if (i < ZERO_U32) p[i] = 0u;
}

// ---------------------------------------------------------------------------
// Kernel 1: edge bucketing (proven r7-r11) + node-role blocks.
// Blocks [0,ABLK): LDS-histogram 391 src-buckets, reserve 64B-aligned runs
// with ONE global atomic per touched bucket, scatter u16 records
// (src&255)<<6|g via LDS cursors, sentinel-pad own gaps.
// Blocks [ABLK,+XBLK): (a) per-graph node counts via sorted-run ballot;
// (b) aggX[g][:] = sum of x rows per graph: 16 waves x 32 sequential nodes,
// float2 run-sum per lane, boundary flush via unsafeAtomicAdd (consecutive
// addresses -> line-merged transactions, r8-proven primitive).
// ---------------------------------------------------------------------------
__global__ __launch_bounds__(1024) void bucket_kernel(
    const int* __restrict__ ei, const int* __restrict__ batch,
    const float* __restrict__ x,
    uint* __restrict__ tail, int* __restrict__ counts,
    float* __restrict__ aggX, ushort* __restrict__ bdata)
{
    const int b = blockIdx.x;
    if (b < ABLK) {
        __shared__ uint hs[NBUCK];
        __shared__ uint he[NBUCK];
        const int t = threadIdx.x;
        for (int i = t; i < NBUCK; i += 1024) hs[i] = 0u;
        __syncthreads();

        const int e0 = b * (1024 * EPT) + t * EPT;
        uint er[EPT];
        int  s[EPT], dn[EPT];
        bool v[EPT];
        if (e0 + EPT <= N_EDGES) {
            const int4 a0 = *reinterpret_cast<const int4*>(ei + e0);
            const int4 a1 = *reinterpret_cast<const int4*>(ei + e0 + 4);
            const int4 b0 = *reinterpret_cast<const int4*>(ei + N_EDGES + e0);
            const int4 b1 = *reinterpret_cast<const int4*>(ei + N_EDGES + e0 + 4);
            s[0]=a0.x; s[1]=a0.y; s[2]=a0.z; s[3]=a0.w;
            s[4]=a1.x; s[5]=a1.y; s[6]=a1.z; s[7]=a1.w;
            dn[0]=b0.x; dn[1]=b0.y; dn[2]=b0.z; dn[3]=b0.w;
            dn[4]=b1.x; dn[5]=b1.y; dn[6]=b1.z; dn[7]=b1.w;
            #pragma unroll
            for (int i = 0; i < EPT; ++i) v[i] = true;
        } else {
            #pragma unroll
            for (int i = 0; i < EPT; ++i) {
                v[i] = (e0 + i) < N_EDGES;
                s[i]  = v[i] ? ei[e0 + i] : 0;
                dn[i] = v[i] ? ei[N_EDGES + e0 + i] : 0;
            }
        }
        #pragma unroll
        for (int i = 0; i < EPT; ++i) {
            if (v[i]) {
                const uint g = (uint)batch[dn[i]];
                const uint k = (uint)s[i] >> 8;
                er[i] = (k << 16) | (((uint)s[i] & 255u) << 6) | g;
                atomicAdd(&hs[k], 1u);
            } else er[i] = 0xFFFFFFFFu;
        }
        __syncthreads();
        if (t < NBUCK) {
            const uint c = hs[t];
            uint r = 0u, a = 0u;
            if (c) { a = (c + 31u) & ~31u; r = atomicAdd(&tail[t], a); }
            hs[t] = r;
            he[t] = r + a;
        }
        __syncthreads();
        #pragma unroll
        for (int i = 0; i < EPT; ++i) {
            if (er[i] != 0xFFFFFFFFu) {
                const uint k = er[i] >> 16;
                const uint pos = atomicAdd(&hs[k], 1u);
                if (pos < BCAP)
                    bdata[(size_t)k * BCAP + pos] = (ushort)(er[i] & 0xFFFFu);
            }
        }
        __syncthreads();
        if (t < NBUCK) {
            uint p = hs[t];
            uint e = he[t];
            if (e > BCAP) e = BCAP;
            for (; p < e; ++p) bdata[(size_t)t * BCAP + p] = 0xFFFFu;
        }
    } else {
        const int nb = b - ABLK;
        const int t  = threadIdx.x;

        // (a) per-graph node counts (waves 0-7, 1 node/thread)
        if (t < 512) {
            const int n = nb * 512 + t;
            if (n < N_NODES) {
                const int lane = t & 63;
                const int g = batch[n];
                const bool lead = (n == 0) || (lane == 0) || (batch[n - 1] != g);
                const ull bl = __ballot(lead);
                if (lead) {
                    const ull higher = (lane == 63) ? 0ull : (bl >> (lane + 1));
                    int end = higher ? (lane + 1 + (__ffsll(higher) - 1)) : 64;
                    const int wb = n - lane;
                    int nv = N_NODES - wb; if (nv > 64) nv = 64;
                    if (end > nv) end = nv;
                    atomicAdd(&counts[g], end - lane);
                }
            }
        }

        // (b) aggX: wave w sums nodes [nb*512 + w*32, +32), lane l dims {2l,2l+1}
        {
            const int w16 = t >> 6, l = t & 63;
            const int n0 = nb * 512 + w16 * 32;
            float2 rs = {0.f, 0.f};
            int cg = -1;
            for (int i = 0; i < 32; ++i) {
                const int n = n0 + i;
                if (n >= N_NODES) break;
                const int g = batch[n];
                const float2 v =
                    *reinterpret_cast<const float2*>(x + (size_t)n * D + 2 * l);
                if (g != cg) {                      // wave-uniform
                    if (cg >= 0) {
                        unsafeAtomicAdd(&aggX[cg * D + 2 * l],     rs.x);
                        unsafeAtomicAdd(&aggX[cg * D + 2 * l + 1], rs.y);
                    }
                    rs.x = 0.f; rs.y = 0.f; cg = g;
                }
                rs.x += v.x; rs.y += v.y;
            }
            if (cg >= 0) {
                unsafeAtomicAdd(&aggX[cg * D + 2 * l],     rs.x);
                unsafeAtomicAdd(&aggX[cg * D + 2 * l + 1], rs.y);
            }
        }
    }
}

// ---------------------------------------------------------------------------
// split-bf16 pack: u32 = bf16_rne(f) | bf16_rne(f - hi) << 16.
// ---------------------------------------------------------------------------
__device__ __forceinline__ uint packbf(float f)
{
    const uint u  = __float_as_uint(f);
    const uint hb = (u + 0x7FFFu + ((u >> 16) & 1u)) >> 16;
    const float hf = __uint_as_float(hb << 16);
    const uint ul = __float_as_uint(f - hf);
    const uint lb = (ul + 0x7FFFu + ((ul >> 16) & 1u)) >> 16;
    return hb | (lb << 16);
}

// ---------------------------------------------------------------------------
// Kernel 2: MFMA GEMM, aggA only (aX path moved to bucket_kernel).
// Per tile (bucket tb>>2, quarter tb&3):
//   ph1: zero h[64][64] + pack-stage x -> xsp          (barrier)
//   ph2: scan bucket records, LDS int atomics into h   (barrier)
//   ph3: ci16[g][node] = bf16(cnt) as u16 — thread (g=t&63, n4=(t>>6)*4)
//        reads 4 h cols (2-way banks), writes one b64   (barrier)
//   ph4: A-fragment = ONE b128 from ci16 (it IS the bhalf8), B from xsp
//        b32-strided as r9-proven; 8 MFMA/wave/tile     (barrier)
// LDS 58.8 KB -> 2 blocks/CU. Counts < 256 exact in bf16 (r9-verified).
// ---------------------------------------------------------------------------
__global__ __launch_bounds__(1024, 8) void gemm_kernel(
    const float* __restrict__ x,
    const uint* __restrict__ tail, const ushort* __restrict__ bdata,
    float* __restrict__ partA, int NBe)
{
    __shared__ uint   xsp[TILE * XSW];    // 33.3 KB
    __shared__ ushort ci16[NG * CIW16];   // 9.2 KB
    __shared__ uint   h[TILE * NG];       // 16 KB

    const int t   = threadIdx.x;
    const int l   = t & 63;
    const int w   = t >> 6;
    const int mt  = w & 3;
    const int nt0 = (w >> 2) << 1;
    const int lr  = l & 15;
    const int lh  = l >> 4;

    f32x4 aA0 = {0,0,0,0}, aA1 = {0,0,0,0};

    const int ntiles = (N_NODES + TILE - 1) / TILE;
    for (int tb = blockIdx.x; tb < ntiles; tb += NBe) {
        const int base   = tb * TILE;
        const int nvalid = min(TILE, N_NODES - base);
        const int bk     = tb >> 2;
        const uint qsel  = (uint)(tb & 3);

        // ---- phase 1: zero h + stage x -> xsp ----
        #pragma unroll
        for (int k = 0; k < 4; ++k) h[t + k * 1024] = 0u;
        #pragma unroll
        for (int k = 0; k < 2; ++k) {
            const int f4i = t + k * 1024;
            const int n = f4i >> 5, c4 = f4i & 31;
            float4 v = make_float4(0.f, 0.f, 0.f, 0.f);
            if (n < nvalid)
                v = *reinterpret_cast<const float4*>(x + (size_t)(base + n) * D + c4 * 4);
            uint2 p01, p23;
            p01.x = packbf(v.x); p01.y = packbf(v.y);
            p23.x = packbf(v.z); p23.y = packbf(v.w);
            uint* dst = xsp + n * XSW + c4 * 4;
            *reinterpret_cast<uint2*>(dst)     = p01;
            *reinterpret_cast<uint2*>(dst + 2) = p23;
        }
        __syncthreads();

        // ---- phase 2: scan bucket records for this quarter ----
        {
            uint nrec = tail[bk]; if (nrec > BCAP) nrec = BCAP;
            const ushort* __restrict__ bp = bdata + (size_t)bk * BCAP;
            for (uint i = (uint)t; i < nrec; i += 1024u) {
                const uint r = bp[i];
                if (r != 0xFFFFu && ((r >> 12) & 3u) == qsel)
                    atomicAdd(&h[((r >> 6) & 63u) * NG + (r & 63u)], 1u);
            }
        }
        __syncthreads();

        // ---- phase 3: ci16[g][node] = bf16(cnt) ----
        {
            const int g  = t & 63;
            const int n4 = (t >> 6) * 4;
            ushort c0 = (ushort)(__float_as_uint((float)h[(n4 + 0) * NG + g]) >> 16);
            ushort c1 = (ushort)(__float_as_uint((float)h[(n4 + 1) * NG + g]) >> 16);
            ushort c2 = (ushort)(__float_as_uint((float)h[(n4 + 2) * NG + g]) >> 16);
            ushort c3 = (ushort)(__float_as_uint((float)h[(n4 + 3) * NG + g]) >> 16);
            uint2 pk;
            pk.x = (uint)c0 | ((uint)c1 << 16);
            pk.y = (uint)c2 | ((uint)c3 << 16);
            *reinterpret_cast<uint2*>(&ci16[g * CIW16 + n4]) = pk;
        }
        __syncthreads();

        // ---- phase 4: MFMA (A = direct b128 bhalf8 from ci16; B as r9) ----
        #pragma unroll
        for (int kc = 0; kc < 2; ++kc) {
            const int k0 = kc * 32;
            const bhalf8 acnt = *reinterpret_cast<const bhalf8*>(
                &ci16[(mt * 16 + lr) * CIW16 + k0 + lh * 8]);

            const uint* xb = xsp + (k0 + lh * 8) * XSW + lr;
            {
                const uint* xp = xb + nt0 * 16;
                const uint r0=xp[0],      r1=xp[XSW],   r2=xp[2*XSW], r3=xp[3*XSW],
                           r4=xp[4*XSW],  r5=xp[5*XSW], r6=xp[6*XSW], r7=xp[7*XSW];
                bhalf8 bh, bl;
                bh[0]=(short)r0; bl[0]=(short)(r0>>16);
                bh[1]=(short)r1; bl[1]=(short)(r1>>16);
                bh[2]=(short)r2; bl[2]=(short)(r2>>16);
                bh[3]=(short)r3; bl[3]=(short)(r3>>16);
                bh[4]=(short)r4; bl[4]=(short)(r4>>16);
                bh[5]=(short)r5; bl[5]=(short)(r5>>16);
                bh[6]=(short)r6; bl[6]=(short)(r6>>16);
                bh[7]=(short)r7; bl[7]=(short)(r7>>16);
                aA0 = MFMA_BF16(acnt, bh, aA0, 0, 0, 0);
                aA0 = MFMA_BF16(acnt, bl, aA0, 0, 0, 0);
            }
            {
                const uint* xp = xb + (nt0 + 1) * 16;
                const uint r0=xp[0],      r1=xp[XSW],   r2=xp[2*XSW], r3=xp[3*XSW],
                           r4=xp[4*XSW],  r5=xp[5*XSW], r6=xp[6*XSW], r7=xp[7*XSW];
                bhalf8 bh, bl;
                bh[0]=(short)r0; bl[0]=(short)(r0>>16);
                bh[1]=(short)r1; bl[1]=(short)(r1>>16);
                bh[2]=(short)r2; bl[2]=(short)(r2>>16);
                bh[3]=(short)r3; bl[3]=(short)(r3>>16);
                bh[4]=(short)r4; bl[4]=(short)(r4>>16);
                bh[5]=(short)r5; bl[5]=(short)(r5>>16);
                bh[6]=(short)r6; bl[6]=(short)(r6>>16);
                bh[7]=(short)r7; bl[7]=(short)(r7>>16);
                aA1 = MFMA_BF16(acnt, bh, aA1, 0, 0, 0);
                aA1 = MFMA_BF16(acnt, bl, aA1, 0, 0, 0);
            }
        }
        __syncthreads();
    }

    // epilogue: C row=(l>>4)*4+r, col=l&15
    float* pa = partA + (size_t)blockIdx.x * (NG * D);
    #pragma unroll
    for (int r = 0; r < 4; ++r) {
        const int row = mt * 16 + lh * 4 + r;
        pa[row * D + nt0 * 16 + lr]       = aA0[r];
        pa[row * D + (nt0 + 1) * 16 + lr] = aA1[r];
    }
}

// ---------------------------------------------------------------------------
// Kernel 3: partial reduction (partA only). 128 blocks = 32 col-blocks x 4
// partial-chunks. Writes tmp2[pc][8192].
// ---------------------------------------------------------------------------
__global__ __launch_bounds__(256) void reduce1_kernel(
    const float* __restrict__ partA, float* __restrict__ tmp2, int NBe)
{
    const int cb = blockIdx.x & 31;
    const int pc = blockIdx.x >> 5;
    const int c  = cb * 256 + threadIdx.x;       // 0..8191
    const int chunk = (NBe + 3) >> 2;
    const int p0 = pc * chunk;
    int p1 = p0 + chunk; if (p1 > NBe) p1 = NBe;
    float s = 0.f;
    #pragma unroll 8
    for (int p = p0; p < p1; ++p) s += partA[(size_t)p * (NG * D) + c];
    tmp2[pc * (NG * D) + c] = s;
}

// ---------------------------------------------------------------------------
// Kernel 4: final 4-way sum + matvec pair + classifier. Block = graph.
// ---------------------------------------------------------------------------
__global__ __launch_bounds__(128) void final_kernel(
    const float* __restrict__ tmp2, const float* __restrict__ aggX,
    const int* __restrict__ counts,
    const float* __restrict__ w_rel, const float* __restrict__ b_rel,
    const float* __restrict__ w_root,
    const float* __restrict__ w_lin, const float* __restrict__ b_lin,
    float* __restrict__ out)
{
    const int g = blockIdx.x;
    const int t = threadIdx.x;   // 0..127

    __shared__ float agg_s[D], x_s[D], p_s[D];
    float a = 0.f;
    #pragma unroll
    for (int j = 0; j < 4; ++j) a += tmp2[j * (NG * D) + g * D + t];
    agg_s[t] = a;
    x_s[t]   = aggX[(size_t)g * D + t];
    __syncthreads();

    const float cn = (float)counts[g];
    float hj = b_rel[t] * cn;
    const float* __restrict__ wr = w_rel  + (size_t)t * D;
    const float* __restrict__ wo = w_root + (size_t)t * D;
    #pragma unroll 8
    for (int d0 = 0; d0 < D; ++d0) hj += agg_s[d0] * wr[d0] + x_s[d0] * wo[d0];
    p_s[t] = hj / fmaxf(cn, 1.f);
    __syncthreads();

    if (t < NC) {
        const float* __restrict__ wl = w_lin + (size_t)t * D;
        float o = b_lin[t];
        #pragma unroll 8
        for (int d0 = 0; d0 < D; ++d0) o += p_s[d0] * wl[d0];
        out[g * NC + t] = o;
    }
}

extern "C" void kernel_launch(void* const* d_in, const int* in_sizes, int n_in,
                              void* d_out, int out_size, void* d_ws, size_t ws_size,
                              hipStream_t stream)
{
    const float* x      = (const float*)d_in[0];
    const int*   ei     = (const int*)  d_in[1];
    const int*   batch  = (const int*)  d_in[2];
    const float* w_rel  = (const float*)d_in[3];
    const float* b_rel  = (const float*)d_in[4];
    const float* w_root = (const float*)d_in[5];
    const float* w_lin  = (const float*)d_in[6];
    const float* b_lin  = (const float*)d_in[7];
    float* out = (float*)d_out;

    // ws layout (u32 units):
    //   [tail 391][counts 64][pad][aggX 8192 f @512][pad -> 8704]
    //   [bdata NBUCK*BCAP/2] [partA NBe*8192 f] [tmp2 4*8192 f]
    uint*   tail   = (uint*)d_ws;
    int*    counts = (int*)(tail + OFF_COUNTS);
    float*  aggX   = (float*)(tail + OFF_AGGX);
    ushort* bdata  = (ushort*)(tail + ZERO_U32);
    float*  partA  = (float*)(tail + ZERO_U32 + BDATA_U32);

    const size_t availf = ws_size / sizeof(float);
    const size_t headf  = ZERO_U32 + BDATA_U32;
    const size_t tmp2f  = 4 * (size_t)(NG * D);
    int NBe = NBMAX;
    if (headf + tmp2f + (size_t)NBe * NG * D > availf) {
        long long rem = (long long)availf - (long long)(headf + tmp2f);
        long long nb  = rem / (NG * D);
        NBe = (nb < 1) ? 1 : (int)nb;
    }
    float* tmp2 = partA + (size_t)NBe * NG * D;

    fill_kernel<<<(ZERO_U32 + 255) / 256, 256, 0, stream>>>(tail);
    bucket_kernel<<<ABLK + XBLK, 1024, 0, stream>>>(ei, batch, x, tail, counts,
                                                    aggX, bdata);
    gemm_kernel<<<NBe, 1024, 0, stream>>>(x, tail, bdata, partA, NBe);
    reduce1_kernel<<<128, 256, 0, stream>>>(partA, tmp2, NBe);
    final_kernel<<<NG, 128, 0, stream>>>(tmp2, aggX, counts,
                                         w_rel, b_rel, w_root, w_lin, b_lin, out);
}

// Round 13
// 77.101 us; speedup vs baseline: 1.1038x; 1.1038x over previous
//
#include <hip/hip_runtime.h>
#include <hip/hip_bf16.h>

#define N_NODES  100000
#define N_EDGES  1600000
#define D        128
#define NG       64
#define NC       10
#define NBMAX    512      // gemm grid: 2 blocks/CU (1024 thr each)
#define TILE     64       // nodes per LDS tile
#define EPT      8        // edges per thread in bucket_kernel
#define ABLK     196      // ceil(N_EDGES / (1024*EPT))
#define NBUCK    391      // ceil(N_NODES / 256) src buckets
#define BCAP     8192     // u16 slots per bucket (empirically sufficient r6-r12)
#define CBLK2    98       // ceil(N_NODES / 1024) node-count blocks
#define CIW16    72       // ci16 row stride (u16): 144B rows -> aligned b128
#define XSW      130      // xsp row stride (u32)

typedef unsigned int uint;
typedef unsigned short ushort;
typedef unsigned long long ull;
typedef short bhalf8 __attribute__((ext_vector_type(8)));
typedef float f32x4  __attribute__((ext_vector_type(4)));

#define MFMA_BF16 __builtin_amdgcn_mfma_f32_16x16x32_bf16

// ws layout (u32 units)
#define OFF_COUNTS 391
#define ZERO_U32   512                    // [tail|counts|pad) zeroed
#define BDATA_U32  (NBUCK * (BCAP / 2))   // 1,601,536

static_assert(ABLK * 1024 * EPT >= N_EDGES, "edge coverage");
static_assert(NBUCK * 256 >= N_NODES, "bucket coverage");

// ---------------------------------------------------------------------------
// Kernel 0: zero tail + counts.
// ---------------------------------------------------------------------------
__global__ __launch_bounds__(256) void fill_kernel(uint* __restrict__ p)
{
    const int i = blockIdx.x * 256 + threadIdx.x;
    if (i < ZERO_U32) p[i] = 0u;
}

// ---------------------------------------------------------------------------
// Kernel 1: edge bucketing (proven r7-r11, r11 form). Blocks [0,ABLK):
// LDS-histogram 391 src-buckets, reserve 64B-aligned runs with ONE global
// atomic per touched bucket, scatter u16 records (src&255)<<6|g via LDS
// cursors, sentinel-pad own gaps. Blocks [ABLK,+CBLK2): per-graph node
// counts via sorted-run ballot.
// ---------------------------------------------------------------------------
__global__ __launch_bounds__(1024) void bucket_kernel(
    const int* __restrict__ ei, const int* __restrict__ batch,
    uint* __restrict__ tail, int* __restrict__ counts,
    ushort* __restrict__ bdata)
{
    const int b = blockIdx.x;
    if (b < ABLK) {
        __shared__ uint hs[NBUCK];
        __shared__ uint he[NBUCK];
        const int t = threadIdx.x;
        for (int i = t; i < NBUCK; i += 1024) hs[i] = 0u;
        __syncthreads();

        const int e0 = b * (1024 * EPT) + t * EPT;
        uint er[EPT];
        int  s[EPT], dn[EPT];
        bool v[EPT];
        if (e0 + EPT <= N_EDGES) {
            const int4 a0 = *reinterpret_cast<const int4*>(ei + e0);
            const int4 a1 = *reinterpret_cast<const int4*>(ei + e0 + 4);
            const int4 b0 = *reinterpret_cast<const int4*>(ei + N_EDGES + e0);
            const int4 b1 = *reinterpret_cast<const int4*>(ei + N_EDGES + e0 + 4);
            s[0]=a0.x; s[1]=a0.y; s[2]=a0.z; s[3]=a0.w;
            s[4]=a1.x; s[5]=a1.y; s[6]=a1.z; s[7]=a1.w;
            dn[0]=b0.x; dn[1]=b0.y; dn[2]=b0.z; dn[3]=b0.w;
            dn[4]=b1.x; dn[5]=b1.y; dn[6]=b1.z; dn[7]=b1.w;
            #pragma unroll
            for (int i = 0; i < EPT; ++i) v[i] = true;
        } else {
            #pragma unroll
            for (int i = 0; i < EPT; ++i) {
                v[i] = (e0 + i) < N_EDGES;
                s[i]  = v[i] ? ei[e0 + i] : 0;
                dn[i] = v[i] ? ei[N_EDGES + e0 + i] : 0;
            }
        }
        #pragma unroll
        for (int i = 0; i < EPT; ++i) {
            if (v[i]) {
                const uint g = (uint)batch[dn[i]];
                const uint k = (uint)s[i] >> 8;
                er[i] = (k << 16) | (((uint)s[i] & 255u) << 6) | g;
                atomicAdd(&hs[k], 1u);
            } else er[i] = 0xFFFFFFFFu;
        }
        __syncthreads();
        if (t < NBUCK) {
            const uint c = hs[t];
            uint r = 0u, a = 0u;
            if (c) { a = (c + 31u) & ~31u; r = atomicAdd(&tail[t], a); }
            hs[t] = r;
            he[t] = r + a;
        }
        __syncthreads();
        #pragma unroll
        for (int i = 0; i < EPT; ++i) {
            if (er[i] != 0xFFFFFFFFu) {
                const uint k = er[i] >> 16;
                const uint pos = atomicAdd(&hs[k], 1u);
                if (pos < BCAP)
                    bdata[(size_t)k * BCAP + pos] = (ushort)(er[i] & 0xFFFFu);
            }
        }
        __syncthreads();
        if (t < NBUCK) {
            uint p = hs[t];
            uint e = he[t];
            if (e > BCAP) e = BCAP;
            for (; p < e; ++p) bdata[(size_t)t * BCAP + p] = 0xFFFFu;
        }
    } else {
        const int n = (b - ABLK) * 1024 + threadIdx.x;
        if (n >= N_NODES) return;
        const int lane = threadIdx.x & 63;
        const int g = batch[n];
        const bool lead = (n == 0) || (lane == 0) || (batch[n - 1] != g);
        const ull bl = __ballot(lead);
        if (lead) {
            const ull higher = (lane == 63) ? 0ull : (bl >> (lane + 1));
            int end = higher ? (lane + 1 + (__ffsll(higher) - 1)) : 64;
            const int wb = n - lane;
            int nv = N_NODES - wb; if (nv > 64) nv = 64;
            if (end > nv) end = nv;
            atomicAdd(&counts[g], end - lane);
        }
    }
}

// ---------------------------------------------------------------------------
// split-bf16 pack via HW casts: u32 = bf16_rne(f) | bf16_rne(f - hi) << 16.
// ---------------------------------------------------------------------------
__device__ __forceinline__ uint packbf(float f)
{
    const __hip_bfloat16 hb = __float2bfloat16(f);          // RNE
    const float hf = __bfloat162float(hb);
    const __hip_bfloat16 lb = __float2bfloat16(f - hf);
    return (uint)__bfloat16_as_ushort(hb) | ((uint)__bfloat16_as_ushort(lb) << 16);
}

// ---------------------------------------------------------------------------
// Kernel 2: MFMA GEMM computing BOTH aggA = cnt.x and aggX = ind.x (r11
// structure) with dual-u16 A-operand arrays:
//   ph1: zero h + pack-stage x -> xsp + stage bs       (barrier)
//   ph2: scan bucket records (quarter tb&3), LDS atomics into h   (barrier)
//   ph3: ci16c[g][n] = bf16(cnt); ci16i[g][n] = bf16(ind)  — b64 writes
//   ph4: A-fragments = ONE b128 each from ci16c/ci16i (they ARE bhalf8);
//        B from xsp strided b32 (r9-proven); 16 MFMA/wave/tile
// LDS 66.8 KB -> 2 blocks/CU. Counts < 256 exact in bf16 (r9-verified).
// ---------------------------------------------------------------------------
__global__ __launch_bounds__(1024, 8) void gemm_kernel(
    const float* __restrict__ x,
    const uint* __restrict__ tail, const ushort* __restrict__ bdata,
    const int* __restrict__ batch,
    float* __restrict__ partA, float* __restrict__ partX, int NBe)
{
    __shared__ uint   xsp[TILE * XSW];     // 33.3 KB
    __shared__ uint   h[TILE * NG];        // 16 KB
    __shared__ ushort ci16c[NG * CIW16];   // 9.2 KB
    __shared__ ushort ci16i[NG * CIW16];   // 9.2 KB
    __shared__ int    bs[TILE];

    const int t   = threadIdx.x;
    const int l   = t & 63;
    const int w   = t >> 6;
    const int mt  = w & 3;
    const int nt0 = (w >> 2) << 1;
    const int lr  = l & 15;
    const int lh  = l >> 4;

    f32x4 aA0 = {0,0,0,0}, aA1 = {0,0,0,0};
    f32x4 aX0 = {0,0,0,0}, aX1 = {0,0,0,0};

    const int ntiles = (N_NODES + TILE - 1) / TILE;
    for (int tb = blockIdx.x; tb < ntiles; tb += NBe) {
        const int base   = tb * TILE;
        const int nvalid = min(TILE, N_NODES - base);
        const int bk     = tb >> 2;
        const uint qsel  = (uint)(tb & 3);

        // ---- phase 1: zero h + stage x -> xsp + stage bs ----
        #pragma unroll
        for (int k = 0; k < 4; ++k) h[t + k * 1024] = 0u;
        #pragma unroll
        for (int k = 0; k < 2; ++k) {
            const int f4i = t + k * 1024;
            const int n = f4i >> 5, c4 = f4i & 31;
            float4 v = make_float4(0.f, 0.f, 0.f, 0.f);
            if (n < nvalid)
                v = *reinterpret_cast<const float4*>(x + (size_t)(base + n) * D + c4 * 4);
            uint2 p01, p23;
            p01.x = packbf(v.x); p01.y = packbf(v.y);
            p23.x = packbf(v.z); p23.y = packbf(v.w);
            uint* dst = xsp + n * XSW + c4 * 4;
            *reinterpret_cast<uint2*>(dst)     = p01;
            *reinterpret_cast<uint2*>(dst + 2) = p23;
        }
        if (t < TILE) bs[t] = (t < nvalid) ? batch[base + t] : -1;
        __syncthreads();

        // ---- phase 2: scan bucket records for this quarter ----
        {
            uint nrec = tail[bk]; if (nrec > BCAP) nrec = BCAP;
            const ushort* __restrict__ bp = bdata + (size_t)bk * BCAP;
            for (uint i = (uint)t; i < nrec; i += 1024u) {
                const uint r = bp[i];
                if (r != 0xFFFFu && ((r >> 12) & 3u) == qsel)
                    atomicAdd(&h[((r >> 6) & 63u) * NG + (r & 63u)], 1u);
            }
        }
        __syncthreads();

        // ---- phase 3: build ci16c (cnt) + ci16i (ind) ----
        {
            const int g  = t & 63;
            const int n4 = (t >> 6) * 4;
            uint2 pc_, pi_;
            uint cc[4], ii[4];
            #pragma unroll
            for (int j = 0; j < 4; ++j) {
                const int node = n4 + j;
                cc[j] = __float_as_uint((float)h[node * NG + g]) >> 16; // exact bf16
                ii[j] = (bs[node] == g) ? 0x3F80u : 0u;                 // bf16(1.0)
            }
            pc_.x = cc[0] | (cc[1] << 16);
            pc_.y = cc[2] | (cc[3] << 16);
            pi_.x = ii[0] | (ii[1] << 16);
            pi_.y = ii[2] | (ii[3] << 16);
            *reinterpret_cast<uint2*>(&ci16c[g * CIW16 + n4]) = pc_;
            *reinterpret_cast<uint2*>(&ci16i[g * CIW16 + n4]) = pi_;
        }
        __syncthreads();

        // ---- phase 4: MFMA (A = direct b128 bhalf8; B as r9) ----
        #pragma unroll
        for (int kc = 0; kc < 2; ++kc) {
            const int k0 = kc * 32;
            const int arow = (mt * 16 + lr) * CIW16 + k0 + lh * 8;
            const bhalf8 acnt = *reinterpret_cast<const bhalf8*>(&ci16c[arow]);
            const bhalf8 aind = *reinterpret_cast<const bhalf8*>(&ci16i[arow]);

            const uint* xb = xsp + (k0 + lh * 8) * XSW + lr;
            {
                const uint* xp = xb + nt0 * 16;
                const uint r0=xp[0],      r1=xp[XSW],   r2=xp[2*XSW], r3=xp[3*XSW],
                           r4=xp[4*XSW],  r5=xp[5*XSW], r6=xp[6*XSW], r7=xp[7*XSW];
                bhalf8 bh, bl;
                bh[0]=(short)r0; bl[0]=(short)(r0>>16);
                bh[1]=(short)r1; bl[1]=(short)(r1>>16);
                bh[2]=(short)r2; bl[2]=(short)(r2>>16);
                bh[3]=(short)r3; bl[3]=(short)(r3>>16);
                bh[4]=(short)r4; bl[4]=(short)(r4>>16);
                bh[5]=(short)r5; bl[5]=(short)(r5>>16);
                bh[6]=(short)r6; bl[6]=(short)(r6>>16);
                bh[7]=(short)r7; bl[7]=(short)(r7>>16);
                aA0 = MFMA_BF16(acnt, bh, aA0, 0, 0, 0);
                aA0 = MFMA_BF16(acnt, bl, aA0, 0, 0, 0);
                aX0 = MFMA_BF16(aind, bh, aX0, 0, 0, 0);
                aX0 = MFMA_BF16(aind, bl, aX0, 0, 0, 0);
            }
            {
                const uint* xp = xb + (nt0 + 1) * 16;
                const uint r0=xp[0],      r1=xp[XSW],   r2=xp[2*XSW], r3=xp[3*XSW],
                           r4=xp[4*XSW],  r5=xp[5*XSW], r6=xp[6*XSW], r7=xp[7*XSW];
                bhalf8 bh, bl;
                bh[0]=(short)r0; bl[0]=(short)(r0>>16);
                bh[1]=(short)r1; bl[1]=(short)(r1>>16);
                bh[2]=(short)r2; bl[2]=(short)(r2>>16);
                bh[3]=(short)r3; bl[3]=(short)(r3>>16);
                bh[4]=(short)r4; bl[4]=(short)(r4>>16);
                bh[5]=(short)r5; bl[5]=(short)(r5>>16);
                bh[6]=(short)r6; bl[6]=(short)(r6>>16);
                bh[7]=(short)r7; bl[7]=(short)(r7>>16);
                aA1 = MFMA_BF16(acnt, bh, aA1, 0, 0, 0);
                aA1 = MFMA_BF16(acnt, bl, aA1, 0, 0, 0);
                aX1 = MFMA_BF16(aind, bh, aX1, 0, 0, 0);
                aX1 = MFMA_BF16(aind, bl, aX1, 0, 0, 0);
            }
        }
        __syncthreads();
    }

    // epilogue: C row=(l>>4)*4+r, col=l&15
    float* pa = partA + (size_t)blockIdx.x * (NG * D);
    float* px = partX + (size_t)blockIdx.x * (NG * D);
    #pragma unroll
    for (int r = 0; r < 4; ++r) {
        const int row = mt * 16 + lh * 4 + r;
        pa[row * D + nt0 * 16 + lr]       = aA0[r];
        pa[row * D + (nt0 + 1) * 16 + lr] = aA1[r];
        px[row * D + nt0 * 16 + lr]       = aX0[r];
        px[row * D + (nt0 + 1) * 16 + lr] = aX1[r];
    }
}

// ---------------------------------------------------------------------------
// Kernel 3: partial reduction, fully coalesced (256 blocks over [A|X]).
// ---------------------------------------------------------------------------
__global__ __launch_bounds__(256) void reduce1_kernel(
    const float* __restrict__ partA, const float* __restrict__ partX,
    float* __restrict__ tmp2, int NBe)
{
    const int cb = blockIdx.x & 63;
    const int pc = blockIdx.x >> 6;
    const int c  = cb * 256 + threadIdx.x;       // 0..16383
    const float* __restrict__ srcp =
        (c < NG * D) ? (partA + c) : (partX + (c - NG * D));
    const int chunk = (NBe + 3) >> 2;
    const int p0 = pc * chunk;
    int p1 = p0 + chunk; if (p1 > NBe) p1 = NBe;
    float s = 0.f;
    #pragma unroll 8
    for (int p = p0; p < p1; ++p) s += srcp[(size_t)p * (NG * D)];
    tmp2[pc * (2 * NG * D) + c] = s;
}

// ---------------------------------------------------------------------------
// Kernel 4: final 4-way sum + matvec pair + classifier. Block = graph.
// ---------------------------------------------------------------------------
__global__ __launch_bounds__(128) void final_kernel(
    const float* __restrict__ tmp2, const int* __restrict__ counts,
    const float* __restrict__ w_rel, const float* __restrict__ b_rel,
    const float* __restrict__ w_root,
    const float* __restrict__ w_lin, const float* __restrict__ b_lin,
    float* __restrict__ out)
{
    const int g = blockIdx.x;
    const int t = threadIdx.x;   // 0..127

    __shared__ float agg_s[D], x_s[D], p_s[D];
    float a = 0.f, xsum = 0.f;
    #pragma unroll
    for (int j = 0; j < 4; ++j) {
        a    += tmp2[j * (2 * NG * D) + g * D + t];
        xsum += tmp2[j * (2 * NG * D) + NG * D + g * D + t];
    }
    agg_s[t] = a; x_s[t] = xsum;
    __syncthreads();

    const float cn = (float)counts[g];
    float hj = b_rel[t] * cn;
    const float* __restrict__ wr = w_rel  + (size_t)t * D;
    const float* __restrict__ wo = w_root + (size_t)t * D;
    #pragma unroll 8
    for (int d0 = 0; d0 < D; ++d0) hj += agg_s[d0] * wr[d0] + x_s[d0] * wo[d0];
    p_s[t] = hj / fmaxf(cn, 1.f);
    __syncthreads();

    if (t < NC) {
        const float* __restrict__ wl = w_lin + (size_t)t * D;
        float o = b_lin[t];
        #pragma unroll 8
        for (int d0 = 0; d0 < D; ++d0) o += p_s[d0] * wl[d0];
        out[g * NC + t] = o;
    }
}

extern "C" void kernel_launch(void* const* d_in, const int* in_sizes, int n_in,
                              void* d_out, int out_size, void* d_ws, size_t ws_size,
                              hipStream_t stream)
{
    const float* x      = (const float*)d_in[0];
    const int*   ei     = (const int*)  d_in[1];
    const int*   batch  = (const int*)  d_in[2];
    const float* w_rel  = (const float*)d_in[3];
    const float* b_rel  = (const float*)d_in[4];
    const float* w_root = (const float*)d_in[5];
    const float* w_lin  = (const float*)d_in[6];
    const float* b_lin  = (const float*)d_in[7];
    float* out = (float*)d_out;

    // ws layout (u32 units):
    //   [tail 391][counts 64][pad -> 512] [bdata NBUCK*BCAP/2]
    //   [partA NBe*8192 f] [partX NBe*8192 f] [tmp2 4*16384 f]
    uint*   tail   = (uint*)d_ws;
    int*    counts = (int*)(tail + OFF_COUNTS);
    ushort* bdata  = (ushort*)(tail + ZERO_U32);
    float*  partA  = (float*)(tail + ZERO_U32 + BDATA_U32);

    const size_t availf = ws_size / sizeof(float);
    const size_t headf  = ZERO_U32 + BDATA_U32;
    const size_t tmp2f  = 4 * (size_t)(2 * NG * D);
    int NBe = NBMAX;
    if (headf + tmp2f + (size_t)NBe * 2 * NG * D > availf) {
        long long rem = (long long)availf - (long long)(headf + tmp2f);
        long long nb  = rem / (2 * NG * D);
        NBe = (nb < 1) ? 1 : (int)nb;
    }
    float* partX = partA + (size_t)NBe * NG * D;
    float* tmp2  = partX + (size_t)NBe * NG * D;

    fill_kernel<<<2, 256, 0, stream>>>(tail);
    bucket_kernel<<<ABLK + CBLK2, 1024, 0, stream>>>(ei, batch, tail, counts, bdata);
    gemm_kernel<<<NBe, 1024, 0, stream>>>(x, tail, bdata, batch, partA, partX, NBe);
    reduce1_kernel<<<256, 256, 0, stream>>>(partA, partX, tmp2, NBe);
    final_kernel<<<NG, 128, 0, stream>>>(tmp2, counts,
                                         w_rel, b_rel, w_root, w_lin, b_lin, out);
}

// Round 14
// 76.736 us; speedup vs baseline: 1.1090x; 1.0048x over previous
//
#include <hip/hip_runtime.h>
#include <hip/hip_bf16.h>

#define N_NODES  100000
#define N_EDGES  1600000
#define D        128
#define NG       64
#define NC       10
#define NBMAX    512      // gemm grid: 2 blocks/CU (1024 thr each)
#define TILE     64       // nodes per LDS tile
#define EPT      8        // edges per thread in bucket_kernel
#define ABLK     196      // ceil(N_EDGES / (1024*EPT))
#define NBUCK    391      // ceil(N_NODES / 256) src buckets
#define BCAP     8192     // u16 slots per bucket (empirically sufficient r6-r13)
#define CBLK2    98       // ceil(N_NODES / 1024) node-count blocks
#define CIW16    72       // ci16 row stride (u16): 144B rows -> aligned b128
#define XSW      130      // xsp row stride (u32)

typedef unsigned int uint;
typedef unsigned short ushort;
typedef unsigned long long ull;
typedef short bhalf8 __attribute__((ext_vector_type(8)));
typedef float f32x4  __attribute__((ext_vector_type(4)));

#define MFMA_BF16 __builtin_amdgcn_mfma_f32_16x16x32_bf16

// ws layout (u32 units)
#define OFF_COUNTS 391
#define ZERO_U32   512                    // [tail|counts|pad) zeroed
#define BDATA_U32  (NBUCK * (BCAP / 2))   // 1,601,536

static_assert(ABLK * 1024 * EPT >= N_EDGES, "edge coverage");
static_assert(NBUCK * 256 >= N_NODES, "bucket coverage");

// ---------------------------------------------------------------------------
// Kernel 0: zero tail + counts.
// ---------------------------------------------------------------------------
__global__ __launch_bounds__(256) void fill_kernel(uint* __restrict__ p)
{
    const int i = blockIdx.x * 256 + threadIdx.x;
    if (i < ZERO_U32) p[i] = 0u;
}

// ---------------------------------------------------------------------------
// Kernel 1: edge bucketing (proven r7-r13). Blocks [0,ABLK): LDS-histogram
// 391 src-buckets, reserve 64B-aligned runs with ONE global atomic per
// touched bucket, scatter u16 records (src&255)<<6|g via LDS cursors,
// sentinel-pad own gaps. Blocks [ABLK,+CBLK2): per-graph node counts.
// ---------------------------------------------------------------------------
__global__ __launch_bounds__(1024) void bucket_kernel(
    const int* __restrict__ ei, const int* __restrict__ batch,
    uint* __restrict__ tail, int* __restrict__ counts,
    ushort* __restrict__ bdata)
{
    const int b = blockIdx.x;
    if (b < ABLK) {
        __shared__ uint hs[NBUCK];
        __shared__ uint he[NBUCK];
        const int t = threadIdx.x;
        for (int i = t; i < NBUCK; i += 1024) hs[i] = 0u;
        __syncthreads();

        const int e0 = b * (1024 * EPT) + t * EPT;
        uint er[EPT];
        int  s[EPT], dn[EPT];
        bool v[EPT];
        if (e0 + EPT <= N_EDGES) {
            const int4 a0 = *reinterpret_cast<const int4*>(ei + e0);
            const int4 a1 = *reinterpret_cast<const int4*>(ei + e0 + 4);
            const int4 b0 = *reinterpret_cast<const int4*>(ei + N_EDGES + e0);
            const int4 b1 = *reinterpret_cast<const int4*>(ei + N_EDGES + e0 + 4);
            s[0]=a0.x; s[1]=a0.y; s[2]=a0.z; s[3]=a0.w;
            s[4]=a1.x; s[5]=a1.y; s[6]=a1.z; s[7]=a1.w;
            dn[0]=b0.x; dn[1]=b0.y; dn[2]=b0.z; dn[3]=b0.w;
            dn[4]=b1.x; dn[5]=b1.y; dn[6]=b1.z; dn[7]=b1.w;
            #pragma unroll
            for (int i = 0; i < EPT; ++i) v[i] = true;
        } else {
            #pragma unroll
            for (int i = 0; i < EPT; ++i) {
                v[i] = (e0 + i) < N_EDGES;
                s[i]  = v[i] ? ei[e0 + i] : 0;
                dn[i] = v[i] ? ei[N_EDGES + e0 + i] : 0;
            }
        }
        #pragma unroll
        for (int i = 0; i < EPT; ++i) {
            if (v[i]) {
                const uint g = (uint)batch[dn[i]];
                const uint k = (uint)s[i] >> 8;
                er[i] = (k << 16) | (((uint)s[i] & 255u) << 6) | g;
                atomicAdd(&hs[k], 1u);
            } else er[i] = 0xFFFFFFFFu;
        }
        __syncthreads();
        if (t < NBUCK) {
            const uint c = hs[t];
            uint r = 0u, a = 0u;
            if (c) { a = (c + 31u) & ~31u; r = atomicAdd(&tail[t], a); }
            hs[t] = r;
            he[t] = r + a;
        }
        __syncthreads();
        #pragma unroll
        for (int i = 0; i < EPT; ++i) {
            if (er[i] != 0xFFFFFFFFu) {
                const uint k = er[i] >> 16;
                const uint pos = atomicAdd(&hs[k], 1u);
                if (pos < BCAP)
                    bdata[(size_t)k * BCAP + pos] = (ushort)(er[i] & 0xFFFFu);
            }
        }
        __syncthreads();
        if (t < NBUCK) {
            uint p = hs[t];
            uint e = he[t];
            if (e > BCAP) e = BCAP;
            for (; p < e; ++p) bdata[(size_t)t * BCAP + p] = 0xFFFFu;
        }
    } else {
        const int n = (b - ABLK) * 1024 + threadIdx.x;
        if (n >= N_NODES) return;
        const int lane = threadIdx.x & 63;
        const int g = batch[n];
        const bool lead = (n == 0) || (lane == 0) || (batch[n - 1] != g);
        const ull bl = __ballot(lead);
        if (lead) {
            const ull higher = (lane == 63) ? 0ull : (bl >> (lane + 1));
            int end = higher ? (lane + 1 + (__ffsll(higher) - 1)) : 64;
            const int wb = n - lane;
            int nv = N_NODES - wb; if (nv > 64) nv = 64;
            if (end > nv) end = nv;
            atomicAdd(&counts[g], end - lane);
        }
    }
}

// ---------------------------------------------------------------------------
// split-bf16 pack via HW casts: u32 = bf16_rne(f) | bf16_rne(f - hi) << 16.
// ---------------------------------------------------------------------------
__device__ __forceinline__ uint packbf(float f)
{
    const __hip_bfloat16 hb = __float2bfloat16(f);          // RNE
    const float hf = __bfloat162float(hb);
    const __hip_bfloat16 lb = __float2bfloat16(f - hf);
    return (uint)__bfloat16_as_ushort(hb) | ((uint)__bfloat16_as_ushort(lb) << 16);
}

// ---------------------------------------------------------------------------
// Kernel 2: MFMA GEMM (aggA = cnt.x, aggX = ind.x), r13 layouts, 3-barrier
// schedule per tile (was 4):
//   prologue: zero h, barrier
//   phase A: stage x -> xsp + SCAN records -> h (disjoint: xsp writes vs h
//            atomics; record loads co-issue with x loads)        [barrier 1]
//   phase B: build ci16c (cnt) / ci16i (ind) from h + bs         [barrier 2]
//   phase C: 16 MFMA (reads xsp, ci16*) + zero h for NEXT tile
//            (h dead after B; zero hides under matrix pipe)      [barrier 3]
// Hazards: C reads xsp / next-A writes xsp (bar3); C zeroes h / next-A
// atomics h (bar3); B reads h / C zeroes h (bar2); A writes bs / B reads
// (bar1). Counts < 256 exact in bf16 (r9-verified).
// ---------------------------------------------------------------------------
__global__ __launch_bounds__(1024, 8) void gemm_kernel(
    const float* __restrict__ x,
    const uint* __restrict__ tail, const ushort* __restrict__ bdata,
    const int* __restrict__ batch,
    float* __restrict__ partA, float* __restrict__ partX, int NBe)
{
    __shared__ uint   xsp[TILE * XSW];     // 33.3 KB
    __shared__ uint   h[TILE * NG];        // 16 KB
    __shared__ ushort ci16c[NG * CIW16];   // 9.2 KB
    __shared__ ushort ci16i[NG * CIW16];   // 9.2 KB
    __shared__ int    bs[TILE];

    const int t   = threadIdx.x;
    const int l   = t & 63;
    const int w   = t >> 6;
    const int mt  = w & 3;
    const int nt0 = (w >> 2) << 1;
    const int lr  = l & 15;
    const int lh  = l >> 4;

    f32x4 aA0 = {0,0,0,0}, aA1 = {0,0,0,0};
    f32x4 aX0 = {0,0,0,0}, aX1 = {0,0,0,0};

    // prologue: zero h once; steady-state re-zero happens in phase C
    #pragma unroll
    for (int k = 0; k < 4; ++k) h[t + k * 1024] = 0u;
    __syncthreads();

    const int ntiles = (N_NODES + TILE - 1) / TILE;
    for (int tb = blockIdx.x; tb < ntiles; tb += NBe) {
        const int base   = tb * TILE;
        const int nvalid = min(TILE, N_NODES - base);
        const int bk     = tb >> 2;
        const uint qsel  = (uint)(tb & 3);

        // ---- phase A: stage x -> xsp  +  scan records -> h ----
        #pragma unroll
        for (int k = 0; k < 2; ++k) {
            const int f4i = t + k * 1024;
            const int n = f4i >> 5, c4 = f4i & 31;
            float4 v = make_float4(0.f, 0.f, 0.f, 0.f);
            if (n < nvalid)
                v = *reinterpret_cast<const float4*>(x + (size_t)(base + n) * D + c4 * 4);
            uint2 p01, p23;
            p01.x = packbf(v.x); p01.y = packbf(v.y);
            p23.x = packbf(v.z); p23.y = packbf(v.w);
            uint* dst = xsp + n * XSW + c4 * 4;
            *reinterpret_cast<uint2*>(dst)     = p01;
            *reinterpret_cast<uint2*>(dst + 2) = p23;
        }
        if (t < TILE) bs[t] = (t < nvalid) ? batch[base + t] : -1;
        {
            uint nrec = tail[bk]; if (nrec > BCAP) nrec = BCAP;
            const ushort* __restrict__ bp = bdata + (size_t)bk * BCAP;
            for (uint i = (uint)t; i < nrec; i += 1024u) {
                const uint r = bp[i];
                if (r != 0xFFFFu && ((r >> 12) & 3u) == qsel)
                    atomicAdd(&h[((r >> 6) & 63u) * NG + (r & 63u)], 1u);
            }
        }
        __syncthreads();                                   // barrier 1

        // ---- phase B: build ci16c (cnt) + ci16i (ind) ----
        {
            const int g  = t & 63;
            const int n4 = (t >> 6) * 4;
            uint2 pc_, pi_;
            uint cc[4], ii[4];
            #pragma unroll
            for (int j = 0; j < 4; ++j) {
                const int node = n4 + j;
                cc[j] = __float_as_uint((float)h[node * NG + g]) >> 16; // exact bf16
                ii[j] = (bs[node] == g) ? 0x3F80u : 0u;                 // bf16(1.0)
            }
            pc_.x = cc[0] | (cc[1] << 16);
            pc_.y = cc[2] | (cc[3] << 16);
            pi_.x = ii[0] | (ii[1] << 16);
            pi_.y = ii[2] | (ii[3] << 16);
            *reinterpret_cast<uint2*>(&ci16c[g * CIW16 + n4]) = pc_;
            *reinterpret_cast<uint2*>(&ci16i[g * CIW16 + n4]) = pi_;
        }
        __syncthreads();                                   // barrier 2

        // ---- phase C: MFMA + zero h for next tile ----
        #pragma unroll
        for (int k = 0; k < 4; ++k) h[t + k * 1024] = 0u;  // hides under MFMA
        #pragma unroll
        for (int kc = 0; kc < 2; ++kc) {
            const int k0 = kc * 32;
            const int arow = (mt * 16 + lr) * CIW16 + k0 + lh * 8;
            const bhalf8 acnt = *reinterpret_cast<const bhalf8*>(&ci16c[arow]);
            const bhalf8 aind = *reinterpret_cast<const bhalf8*>(&ci16i[arow]);

            const uint* xb = xsp + (k0 + lh * 8) * XSW + lr;
            {
                const uint* xp = xb + nt0 * 16;
                const uint r0=xp[0],      r1=xp[XSW],   r2=xp[2*XSW], r3=xp[3*XSW],
                           r4=xp[4*XSW],  r5=xp[5*XSW], r6=xp[6*XSW], r7=xp[7*XSW];
                bhalf8 bh, bl;
                bh[0]=(short)r0; bl[0]=(short)(r0>>16);
                bh[1]=(short)r1; bl[1]=(short)(r1>>16);
                bh[2]=(short)r2; bl[2]=(short)(r2>>16);
                bh[3]=(short)r3; bl[3]=(short)(r3>>16);
                bh[4]=(short)r4; bl[4]=(short)(r4>>16);
                bh[5]=(short)r5; bl[5]=(short)(r5>>16);
                bh[6]=(short)r6; bl[6]=(short)(r6>>16);
                bh[7]=(short)r7; bl[7]=(short)(r7>>16);
                aA0 = MFMA_BF16(acnt, bh, aA0, 0, 0, 0);
                aA0 = MFMA_BF16(acnt, bl, aA0, 0, 0, 0);
                aX0 = MFMA_BF16(aind, bh, aX0, 0, 0, 0);
                aX0 = MFMA_BF16(aind, bl, aX0, 0, 0, 0);
            }
            {
                const uint* xp = xb + (nt0 + 1) * 16;
                const uint r0=xp[0],      r1=xp[XSW],   r2=xp[2*XSW], r3=xp[3*XSW],
                           r4=xp[4*XSW],  r5=xp[5*XSW], r6=xp[6*XSW], r7=xp[7*XSW];
                bhalf8 bh, bl;
                bh[0]=(short)r0; bl[0]=(short)(r0>>16);
                bh[1]=(short)r1; bl[1]=(short)(r1>>16);
                bh[2]=(short)r2; bl[2]=(short)(r2>>16);
                bh[3]=(short)r3; bl[3]=(short)(r3>>16);
                bh[4]=(short)r4; bl[4]=(short)(r4>>16);
                bh[5]=(short)r5; bl[5]=(short)(r5>>16);
                bh[6]=(short)r6; bl[6]=(short)(r6>>16);
                bh[7]=(short)r7; bl[7]=(short)(r7>>16);
                aA1 = MFMA_BF16(acnt, bh, aA1, 0, 0, 0);
                aA1 = MFMA_BF16(acnt, bl, aA1, 0, 0, 0);
                aX1 = MFMA_BF16(aind, bh, aX1, 0, 0, 0);
                aX1 = MFMA_BF16(aind, bl, aX1, 0, 0, 0);
            }
        }
        __syncthreads();                                   // barrier 3
    }

    // epilogue: C row=(l>>4)*4+r, col=l&15
    float* pa = partA + (size_t)blockIdx.x * (NG * D);
    float* px = partX + (size_t)blockIdx.x * (NG * D);
    #pragma unroll
    for (int r = 0; r < 4; ++r) {
        const int row = mt * 16 + lh * 4 + r;
        pa[row * D + nt0 * 16 + lr]       = aA0[r];
        pa[row * D + (nt0 + 1) * 16 + lr] = aA1[r];
        px[row * D + nt0 * 16 + lr]       = aX0[r];
        px[row * D + (nt0 + 1) * 16 + lr] = aX1[r];
    }
}

// ---------------------------------------------------------------------------
// Kernel 3: partial reduction, fully coalesced (256 blocks over [A|X]).
// ---------------------------------------------------------------------------
__global__ __launch_bounds__(256) void reduce1_kernel(
    const float* __restrict__ partA, const float* __restrict__ partX,
    float* __restrict__ tmp2, int NBe)
{
    const int cb = blockIdx.x & 63;
    const int pc = blockIdx.x >> 6;
    const int c  = cb * 256 + threadIdx.x;       // 0..16383
    const float* __restrict__ srcp =
        (c < NG * D) ? (partA + c) : (partX + (c - NG * D));
    const int chunk = (NBe + 3) >> 2;
    const int p0 = pc * chunk;
    int p1 = p0 + chunk; if (p1 > NBe) p1 = NBe;
    float s = 0.f;
    #pragma unroll 8
    for (int p = p0; p < p1; ++p) s += srcp[(size_t)p * (NG * D)];
    tmp2[pc * (2 * NG * D) + c] = s;
}

// ---------------------------------------------------------------------------
// Kernel 4: final 4-way sum + matvec pair + classifier. Block = graph.
// ---------------------------------------------------------------------------
__global__ __launch_bounds__(128) void final_kernel(
    const float* __restrict__ tmp2, const int* __restrict__ counts,
    const float* __restrict__ w_rel, const float* __restrict__ b_rel,
    const float* __restrict__ w_root,
    const float* __restrict__ w_lin, const float* __restrict__ b_lin,
    float* __restrict__ out)
{
    const int g = blockIdx.x;
    const int t = threadIdx.x;   // 0..127

    __shared__ float agg_s[D], x_s[D], p_s[D];
    float a = 0.f, xsum = 0.f;
    #pragma unroll
    for (int j = 0; j < 4; ++j) {
        a    += tmp2[j * (2 * NG * D) + g * D + t];
        xsum += tmp2[j * (2 * NG * D) + NG * D + g * D + t];
    }
    agg_s[t] = a; x_s[t] = xsum;
    __syncthreads();

    const float cn = (float)counts[g];
    float hj = b_rel[t] * cn;
    const float* __restrict__ wr = w_rel  + (size_t)t * D;
    const float* __restrict__ wo = w_root + (size_t)t * D;
    #pragma unroll 8
    for (int d0 = 0; d0 < D; ++d0) hj += agg_s[d0] * wr[d0] + x_s[d0] * wo[d0];
    p_s[t] = hj / fmaxf(cn, 1.f);
    __syncthreads();

    if (t < NC) {
        const float* __restrict__ wl = w_lin + (size_t)t * D;
        float o = b_lin[t];
        #pragma unroll 8
        for (int d0 = 0; d0 < D; ++d0) o += p_s[d0] * wl[d0];
        out[g * NC + t] = o;
    }
}

extern "C" void kernel_launch(void* const* d_in, const int* in_sizes, int n_in,
                              void* d_out, int out_size, void* d_ws, size_t ws_size,
                              hipStream_t stream)
{
    const float* x      = (const float*)d_in[0];
    const int*   ei     = (const int*)  d_in[1];
    const int*   batch  = (const int*)  d_in[2];
    const float* w_rel  = (const float*)d_in[3];
    const float* b_rel  = (const float*)d_in[4];
    const float* w_root = (const float*)d_in[5];
    const float* w_lin  = (const float*)d_in[6];
    const float* b_lin  = (const float*)d_in[7];
    float* out = (float*)d_out;

    // ws layout (u32 units):
    //   [tail 391][counts 64][pad -> 512] [bdata NBUCK*BCAP/2]
    //   [partA NBe*8192 f] [partX NBe*8192 f] [tmp2 4*16384 f]
    uint*   tail   = (uint*)d_ws;
    int*    counts = (int*)(tail + OFF_COUNTS);
    ushort* bdata  = (ushort*)(tail + ZERO_U32);
    float*  partA  = (float*)(tail + ZERO_U32 + BDATA_U32);

    const size_t availf = ws_size / sizeof(float);
    const size_t headf  = ZERO_U32 + BDATA_U32;
    const size_t tmp2f  = 4 * (size_t)(2 * NG * D);
    int NBe = NBMAX;
    if (headf + tmp2f + (size_t)NBe * 2 * NG * D > availf) {
        long long rem = (long long)availf - (long long)(headf + tmp2f);
        long long nb  = rem / (2 * NG * D);
        NBe = (nb < 1) ? 1 : (int)nb;
    }
    float* partX = partA + (size_t)NBe * NG * D;
    float* tmp2  = partX + (size_t)NBe * NG * D;

    fill_kernel<<<2, 256, 0, stream>>>(tail);
    bucket_kernel<<<ABLK + CBLK2, 1024, 0, stream>>>(ei, batch, tail, counts, bdata);
    gemm_kernel<<<NBe, 1024, 0, stream>>>(x, tail, bdata, batch, partA, partX, NBe);
    reduce1_kernel<<<256, 256, 0, stream>>>(partA, partX, tmp2, NBe);
    final_kernel<<<NG, 128, 0, stream>>>(tmp2, counts,
                                         w_rel, b_rel, w_root, w_lin, b_lin, out);
}